// Round 23
// baseline (315.843 us; speedup 1.0000x reference)
//
#include <hip/hip_runtime.h>

typedef _Float16 half8 __attribute__((ext_vector_type(8)));
typedef float f32x2 __attribute__((ext_vector_type(2)));
typedef float f32x4 __attribute__((ext_vector_type(4)));
typedef float f32x16 __attribute__((ext_vector_type(16)));

#define DIM 256
#define NE 1024
#define NROWS 131072
#define DECAY 0.99f
#define ONE_MINUS 0.01f
#define EPS 1e-5f

// output offsets (floats) in d_out, concatenated in reference return order
#define OFF_Q    0u
#define OFF_DIFF 33554432u
#define OFF_IND  33554433u
#define OFF_NEMB 33685505u
#define OFF_NCS  33947649u
#define OFF_NEA  33948673u

#define MFMA32(a, b, c) __builtin_amdgcn_mfma_f32_32x32x16_f16(a, b, c, 0, 0, 0)

#define GLOAD16(gp, lp) __builtin_amdgcn_global_load_lds( \
    (__attribute__((address_space(1))) const void*)(gp),  \
    (__attribute__((address_space(3))) void*)(lp), 16, 0, 0)

// (distance, idx) -> u32 key; distances strictly positive -> IEEE bits
// monotonic. Low 10 mantissa bits carry idx (granularity ~0.016 << f16 noise).
static __device__ __forceinline__ unsigned packkey32(float v, int idx) {
    return (__float_as_uint(v) & 0xFFFFFC00u) | (unsigned)idx;
}
#define UMIN(a, b) ((b) < (a) ? (b) : (a))

// ---------------- K0_all: prep(64 blocks) + cvt(16384 blocks) + zeroing --------
// blocks 0..63: codebook transpose -> bt_hi/embT + per-d-block sq partials.
// blocks 64..: input f32 -> f16 fragment-major qhiT; first 8 also zero
// counts/cursors/donecnt. NOTE: in-kernel conversion inside k1 does NOT fit
// the unified reg file (A=64 + 64 arch = full 128 bucket; R21 spilled 178MB).
__global__ void k0_all(const float* __restrict__ embed,
                       const float* __restrict__ input,
                       _Float16* __restrict__ bt_hi,
                       float* __restrict__ embT,
                       float* __restrict__ sqpart,
                       _Float16* __restrict__ qhiT,
                       int* __restrict__ counts,
                       int* __restrict__ cursors,
                       int* __restrict__ donecnt) {
    int t = threadIdx.x;
    if (blockIdx.x < 64) {
        __shared__ float T[64][65];
        int db = blockIdx.x & 3;
        int j0 = (blockIdx.x >> 2) * 64, d0 = db * 64;
        #pragma unroll
        for (int p = 0; p < 16; ++p) {
            int dd = p * 4 + (t >> 6), jj = t & 63;
            T[jj][dd] = embed[(size_t)(d0 + dd) * NE + j0 + jj];
        }
        __syncthreads();
        #pragma unroll
        for (int p = 0; p < 16; ++p) {
            int jj = p * 4 + (t >> 6), dd = t & 63;
            float e = T[jj][dd];
            int j = j0 + jj, d = d0 + dd;
            embT[(size_t)j * DIM + d] = e;
            bt_hi[(size_t)j * DIM + d] = (_Float16)e;
            float s = e * e;
            #pragma unroll
            for (int off = 32; off; off >>= 1) s += __shfl_down(s, off);
            if ((t & 63) == 0) sqpart[db * NE + j] = 0.5f * s;   // lane0 of wave
        }
    } else {
        int bc = blockIdx.x - 64;
        if (bc < 4) counts[bc * 256 + t] = 0;
        else if (bc < 8) cursors[(bc - 4) * 256 + t] = 0;
        if (bc == 8 && t == 0) *donecnt = 0;
        size_t D8 = (size_t)bc * 256 + t;   // half8 index
        int f = (int)(D8 >> 6);
        int lane = (int)(D8 & 63);
        int row = (f >> 4) * 32 + (lane & 31);
        int d = (f & 15) * 16 + (lane >> 5) * 8;
        const float* src = input + (size_t)row * DIM + d;
        f32x4 a = *(const f32x4*)src;
        f32x4 b = *(const f32x4*)(src + 4);
        half8 h;
        h[0] = (_Float16)a[0]; h[1] = (_Float16)a[1];
        h[2] = (_Float16)a[2]; h[3] = (_Float16)a[3];
        h[4] = (_Float16)b[0]; h[5] = (_Float16)b[1];
        h[6] = (_Float16)b[2]; h[7] = (_Float16)b[3];
        *(half8*)(qhiT + D8 * 8) = h;
    }
}

// ---------------- K1: code-resident GEMM, 8 waves share each LDS tile ---------
// 512 thr = 8 waves x 32 codes (A in AGPRs, 64 + ~60 arch = 124 unified ->
// 128-bucket -> 4 waves/EU -> 2 blocks/CU = 16 waves). Counted vmcnt(2),
// 2-deep dbuf. DO NOT request >4 waves/EU: A alone is 64 regs (R17 spill).
__global__ __launch_bounds__(512, 4)
void k1_stream(const _Float16* __restrict__ qhiT,
               const _Float16* __restrict__ bt_hi,
               const float* __restrict__ sqp,
               unsigned* __restrict__ part) {
    __shared__ _Float16 Xb[2][8192];            // 2 x 16KB m-tile
    const int b = blockIdx.x;
    const int q = (b >> 3) & 3;                 // code-block 0..3 (256 codes)
    const int r = (b & 7) + ((b >> 5) << 3);    // rowchunk 0..511 (XCD-colocated)
    const int tid = threadIdx.x;
    const int w = tid >> 6, l = tid & 63;
    const int l31 = l & 31, h = l >> 5;
    const int cq = q * 256 + w * 32;            // wave's 32 codes
    const size_t tbase = (size_t)(r * 8) * 8192;  // halves; tile t at + t*8192

#define STAGE(t, bf) do {                                                  \
    const _Float16* sp_ = qhiT + tbase + (size_t)(t) * 8192 + tid * 8;     \
    _Float16* dp_ = &Xb[bf][tid * 8];                                      \
    GLOAD16(sp_ + 0,    dp_ + 0);                                          \
    GLOAD16(sp_ + 4096, dp_ + 4096);                                       \
} while (0)

    STAGE(0, 0);
    STAGE(1, 1);

    // A: lane holds code cq+l31, k-slice kb*16 + h*8 + 0..7 (loaded once)
    half8 A[16];
    {
        const _Float16* ap = bt_hi + (size_t)(cq + l31) * DIM + h * 8;
        #pragma unroll
        for (int kb = 0; kb < 16; ++kb) A[kb] = *(const half8*)(ap + kb * 16);
    }
    // sq for the lane's 16 D-rows: code = cq + (rr&3) + 8*(rr>>2) + 4*h
    float sq[16];
    #pragma unroll
    for (int rr = 0; rr < 16; ++rr) {
        int c = cq + (rr & 3) + 8 * (rr >> 2) + 4 * h;
        sq[rr] = (sqp[c] + sqp[NE + c]) + (sqp[2 * NE + c] + sqp[3 * NE + c]);
    }
    const int ibase = cq + 4 * h;

    __syncthreads();   // one-time full drain: tiles 0,1 + A + sq

    unsigned keys[8];
    int buf = 0;
    #pragma unroll
    for (int m = 0; m < 8; ++m) {
        // own 2 tile-m loads landed; tile m+1's 2 stay in flight
        if (m == 7) { asm volatile("s_waitcnt vmcnt(0)" ::: "memory"); }
        else        { asm volatile("s_waitcnt vmcnt(2)" ::: "memory"); }
        __builtin_amdgcn_s_barrier();

        const _Float16* X = &Xb[buf][l * 8];
        f32x16 acc;
        #pragma unroll
        for (int e = 0; e < 16; ++e) acc[e] = 0.f;
        __builtin_amdgcn_s_setprio(1);
        #pragma unroll
        for (int kb = 0; kb < 16; ++kb) {
            half8 x = *(const half8*)(X + kb * 512);
            acc = MFMA32(A[kb], x, acc);
        }
        __builtin_amdgcn_s_setprio(0);
        __builtin_amdgcn_s_barrier();   // all waves done reading Xb[buf]

        // stage tile m+2 into the buffer just consumed
        if (m < 6) STAGE(m + 2, buf);

        // u32-key tree-min over the lane's 16 codes (register-only)
        unsigned k0 = packkey32(sq[0] - acc[0], ibase + 0);
        unsigned k1 = packkey32(sq[1] - acc[1], ibase + 1);
        unsigned k2 = packkey32(sq[2] - acc[2], ibase + 2);
        unsigned k3 = packkey32(sq[3] - acc[3], ibase + 3);
        unsigned k4 = packkey32(sq[4] - acc[4], ibase + 8);
        unsigned k5 = packkey32(sq[5] - acc[5], ibase + 9);
        unsigned k6 = packkey32(sq[6] - acc[6], ibase + 10);
        unsigned k7 = packkey32(sq[7] - acc[7], ibase + 11);
        unsigned k8 = packkey32(sq[8] - acc[8], ibase + 16);
        unsigned k9 = packkey32(sq[9] - acc[9], ibase + 17);
        unsigned ka = packkey32(sq[10] - acc[10], ibase + 18);
        unsigned kb_ = packkey32(sq[11] - acc[11], ibase + 19);
        unsigned kc = packkey32(sq[12] - acc[12], ibase + 24);
        unsigned kd = packkey32(sq[13] - acc[13], ibase + 25);
        unsigned ke = packkey32(sq[14] - acc[14], ibase + 26);
        unsigned kf = packkey32(sq[15] - acc[15], ibase + 27);
        k0 = UMIN(k0, k1); k2 = UMIN(k2, k3);
        k4 = UMIN(k4, k5); k6 = UMIN(k6, k7);
        k8 = UMIN(k8, k9); ka = UMIN(ka, kb_);
        kc = UMIN(kc, kd); ke = UMIN(ke, kf);
        k0 = UMIN(k0, k2); k4 = UMIN(k4, k6);
        k8 = UMIN(k8, ka); kc = UMIN(kc, ke);
        k0 = UMIN(k0, k4); k8 = UMIN(k8, kc);
        keys[m] = UMIN(k0, k8);

        buf ^= 1;
    }

    // batched cross-lane merge: lanes l and l+32 share input row (col = l31)
    #pragma unroll
    for (int m = 0; m < 8; ++m) {
        unsigned ok = __shfl_xor(keys[m], 32);
        keys[m] = UMIN(keys[m], ok);
    }
    if (l < 32) {
        unsigned* pout = part + (size_t)(q * 8 + w) * NROWS + r * 256 + l31;
        #pragma unroll
        for (int m = 0; m < 8; ++m) pout[m * 32] = keys[m];
    }
}

// ---------------- K1b: partials -> index/hist + zero esum; LAST block runs K2 --
// 128 blocks x 1024 thr (1 row/thread). After the histogram atomics land, the
// last-finished block executes the scan/EMA-scalar body (identical math to the
// old k2_small; counts read via device-scope atomics -> no stale-L1 risk).
__global__ __launch_bounds__(1024)
void k1b_idx(const unsigned* __restrict__ part,
             const float* __restrict__ cluster_size,
             float* __restrict__ out,
             int* __restrict__ jint,
             int* __restrict__ counts,
             float* __restrict__ embed_sum,
             int* __restrict__ offsets,
             float* __restrict__ cs_ws,
             int* __restrict__ donecnt) {
    __shared__ int   wtot[16];
    __shared__ float wsum[16];
    __shared__ int lastflag;
    int t = threadIdx.x;
    int row = blockIdx.x * 1024 + t;
    // zero embed_sum inline (bt_hi overlay dead after k1_stream)
    ((f32x2*)embed_sum)[row] = (f32x2){0.f, 0.f};
    unsigned best = part[row];
    #pragma unroll
    for (int qw = 1; qw < 32; ++qw) {
        unsigned v = part[(size_t)qw * NROWS + row];
        best = UMIN(best, v);
    }
    int jm = (int)(best & 0x3FFu);
    out[OFF_IND + row] = (float)jm;
    jint[row] = jm;
    atomicAdd(&counts[jm], 1);

    // last-block election (saves one kernel-launch boundary)
    __threadfence();
    __syncthreads();
    if (t == 0) lastflag = (atomicAdd(donecnt, 1) == 127) ? 1 : 0;
    __syncthreads();
    if (!lastflag) return;

    // ---- K2 body (identical math to the former k2_small) ----
    int w = t >> 6, l = t & 63;
    int cnt = atomicAdd(&counts[t], 0);   // device-scope read
    float ncs = cluster_size[t] * DECAY + ONE_MINUS * (float)cnt;
    out[OFF_NCS + t] = ncs;

    int sc = cnt;
    #pragma unroll
    for (int off = 1; off < 64; off <<= 1) {
        int v = __shfl_up(sc, off);
        if (l >= off) sc += v;
    }
    float ws = ncs;
    #pragma unroll
    for (int off = 32; off; off >>= 1) ws += __shfl_xor(ws, off);
    if (l == 63) wtot[w] = sc;
    if (l == 0) wsum[w] = ws;
    __syncthreads();
    int woff = 0; float n = 0.f;
    #pragma unroll
    for (int i = 0; i < 16; ++i) {
        woff += (i < w) ? wtot[i] : 0;
        n += wsum[i];
    }
    offsets[t] = woff + sc - cnt;       // exclusive prefix
    cs_ws[t] = (ncs + EPS) / (n + (float)NE * EPS) * n;
}

// ---------------- K3: scatter row ids into per-code buckets ----------------
__global__ void k3_scatter(const int* __restrict__ jint,
                           const int* __restrict__ offsets,
                           int* __restrict__ cursors,
                           int* __restrict__ list) {
    int r = blockIdx.x * 256 + threadIdx.x;
    int j = jint[r];
    int pos = atomicAdd(&cursors[j], 1);
    list[offsets[j] + pos] = r;
}

// ---------------- K4: FUSED balanced segment sum + quantize write + diff ------
#define K4FLUSH() do {                                                   \
    float* dst = embed_sum + (size_t)curj * DIM + l * 4;                 \
    atomicAdd(dst + 0, acc[0]); atomicAdd(dst + 1, acc[1]);              \
    atomicAdd(dst + 2, acc[2]); atomicAdd(dst + 3, acc[3]);              \
    acc[0] = acc[1] = acc[2] = acc[3] = 0.f;                             \
} while (0)

__global__ void k4_segsum(const float* __restrict__ input,
                          const int* __restrict__ jint,
                          const int* __restrict__ list,
                          const float* __restrict__ embT,
                          float* __restrict__ out,
                          float* __restrict__ embed_sum,
                          float* __restrict__ diffpart) {
    __shared__ float dred[4];
    int wid = (blockIdx.x * 256 + threadIdx.x) >> 6;   // 0..4095
    int w = (threadIdx.x >> 6), l = threadIdx.x & 63;
    int p0 = wid * 32;
    int row_l = list[p0 + (l & 31)];
    int j_l = jint[row_l];
    f32x4 acc = {0.f, 0.f, 0.f, 0.f};
    float dsum = 0.f;
    int curj = __shfl(j_l, 0);
    #pragma unroll 1
    for (int g = 0; g < 8; ++g) {
        int r0 = __shfl(row_l, 4 * g + 0), j0 = __shfl(j_l, 4 * g + 0);
        int r1 = __shfl(row_l, 4 * g + 1), j1 = __shfl(j_l, 4 * g + 1);
        int r2 = __shfl(row_l, 4 * g + 2), j2 = __shfl(j_l, 4 * g + 2);
        int r3 = __shfl(row_l, 4 * g + 3), j3 = __shfl(j_l, 4 * g + 3);
        f32x4 v0 = *(const f32x4*)(input + (size_t)r0 * DIM + l * 4);
        f32x4 v1 = *(const f32x4*)(input + (size_t)r1 * DIM + l * 4);
        f32x4 v2 = *(const f32x4*)(input + (size_t)r2 * DIM + l * 4);
        f32x4 v3 = *(const f32x4*)(input + (size_t)r3 * DIM + l * 4);
        f32x4 q0 = *(const f32x4*)(embT + (size_t)j0 * DIM + l * 4);
        f32x4 q1 = *(const f32x4*)(embT + (size_t)j1 * DIM + l * 4);
        f32x4 q2 = *(const f32x4*)(embT + (size_t)j2 * DIM + l * 4);
        f32x4 q3 = *(const f32x4*)(embT + (size_t)j3 * DIM + l * 4);
        *(f32x4*)(out + OFF_Q + (size_t)r0 * DIM + l * 4) = q0;
        *(f32x4*)(out + OFF_Q + (size_t)r1 * DIM + l * 4) = q1;
        *(f32x4*)(out + OFF_Q + (size_t)r2 * DIM + l * 4) = q2;
        *(f32x4*)(out + OFF_Q + (size_t)r3 * DIM + l * 4) = q3;
        f32x4 e0 = q0 - v0, e1 = q1 - v1, e2 = q2 - v2, e3 = q3 - v3;
        dsum += e0[0]*e0[0] + e0[1]*e0[1] + e0[2]*e0[2] + e0[3]*e0[3];
        dsum += e1[0]*e1[0] + e1[1]*e1[1] + e1[2]*e1[2] + e1[3]*e1[3];
        dsum += e2[0]*e2[0] + e2[1]*e2[1] + e2[2]*e2[2] + e2[3]*e2[3];
        dsum += e3[0]*e3[0] + e3[1]*e3[1] + e3[2]*e3[2] + e3[3]*e3[3];
        if (j0 != curj) { K4FLUSH(); curj = j0; }
        acc += v0;
        if (j1 != curj) { K4FLUSH(); curj = j1; }
        acc += v1;
        if (j2 != curj) { K4FLUSH(); curj = j2; }
        acc += v2;
        if (j3 != curj) { K4FLUSH(); curj = j3; }
        acc += v3;
    }
    K4FLUSH();
    for (int off = 32; off; off >>= 1) dsum += __shfl_down(dsum, off);
    if (l == 0) dred[w] = dsum;
    __syncthreads();
    if (threadIdx.x == 0)
        diffpart[blockIdx.x] = dred[0] + dred[1] + dred[2] + dred[3];
}

// ---------------- K5: transpose + EMA outputs + diff finalize (merged) --------
__global__ void k5_ema(const float* __restrict__ embed_sum,
                       const float* __restrict__ embed_avg,
                       const float* __restrict__ cs_ws,
                       const float* __restrict__ diffpart,
                       float* __restrict__ out) {
    __shared__ float T[64][65];
    __shared__ float dsh[4];
    int t = threadIdx.x;
    bool b0 = (blockIdx.x == 0) && (blockIdx.y == 0);
    if (b0) {
        float dp = (diffpart[t] + diffpart[t + 256])
                 + (diffpart[t + 512] + diffpart[t + 768]);
        #pragma unroll
        for (int off = 32; off; off >>= 1) dp += __shfl_xor(dp, off);
        if ((t & 63) == 0) dsh[t >> 6] = dp;
    }
    int j0 = blockIdx.x * 64, d0 = blockIdx.y * 64;
    #pragma unroll
    for (int p = 0; p < 16; ++p) {
        int jj = p * 4 + (t >> 6), dd = t & 63;
        T[dd][jj] = embed_sum[(size_t)(j0 + jj) * DIM + d0 + dd];
    }
    __syncthreads();
    if (b0 && t == 0)
        out[OFF_DIFF] = ((dsh[0] + dsh[1]) + (dsh[2] + dsh[3])) / 33554432.0f;
    #pragma unroll
    for (int p = 0; p < 16; ++p) {
        int dd = p * 4 + (t >> 6), jj = t & 63;
        int d = d0 + dd, j = j0 + jj;
        float sum = T[dd][jj];
        float na = embed_avg[(size_t)d * NE + j] * DECAY + ONE_MINUS * sum;
        out[OFF_NEA + (size_t)d * NE + j] = na;
        out[OFF_NEMB + (size_t)d * NE + j] = na / cs_ws[j];
    }
}

extern "C" void kernel_launch(void* const* d_in, const int* in_sizes, int n_in,
                              void* d_out, int out_size, void* d_ws, size_t ws_size,
                              hipStream_t stream) {
    const float* input        = (const float*)d_in[0];
    const float* embed        = (const float*)d_in[1];
    const float* cluster_size = (const float*)d_in[2];
    const float* embed_avg    = (const float*)d_in[3];
    float* out = (float*)d_out;
    char* ws = (char*)d_ws;

    _Float16* bt_hi  = (_Float16*)(ws + 0);             // 512 KB
    float*    embT   = (float*)(ws + 1048576);          // 1 MB
    int*      counts = (int*)(ws + 2101248);
    int*      offsets= (int*)(ws + 2105344);
    int*      cursors= (int*)(ws + 2113536);
    int*      jint   = (int*)(ws + 2117632);            // 512 KB
    int*      list   = (int*)(ws + 2641920);            // 512 KB
    float*    diffpart = (float*)(ws + 3166208);        // 1024 floats
    float*    cs_ws  = (float*)(ws + 3174400);          // 4 KB
    float*    sqpart = (float*)(ws + 3178496);          // 16 KB
    int*      donecnt = (int*)(ws + 3194880);           // 4 B
    // embed_sum overlays the dead bt_hi region after k1_stream
    float*    embed_sum = (float*)(ws + 0);             // [1024][256] f32
    // scratch inside the out-Q region (dead before k4 writes Q):
    //   qhiT: fragment-major f16 input plane, 64 MiB at Q[0..)
    //   part: 32 u32 partial keys per row, 16 MiB at Q+64MiB
    _Float16* qhiT = (_Float16*)(out + OFF_Q);
    unsigned* part = (unsigned*)((char*)(out + OFF_Q) + (64u << 20));

    k0_all<<<16448, 256, 0, stream>>>(embed, input, bt_hi, embT, sqpart,
                                      qhiT, counts, cursors, donecnt);
    k1_stream<<<2048, 512, 0, stream>>>(qhiT, bt_hi, sqpart, part);
    k1b_idx<<<128, 1024, 0, stream>>>(part, cluster_size, out, jint, counts,
                                      embed_sum, offsets, cs_ws, donecnt);
    k3_scatter<<<512, 256, 0, stream>>>(jint, offsets, cursors, list);
    k4_segsum<<<1024, 256, 0, stream>>>(input, jint, list, embT, out, embed_sum, diffpart);
    k5_ema<<<dim3(16, 4), 256, 0, stream>>>(embed_sum, embed_avg, cs_ws, diffpart, out);
}

// Round 24
// 315.507 us; speedup vs baseline: 1.0011x; 1.0011x over previous
//
#include <hip/hip_runtime.h>

typedef _Float16 half8 __attribute__((ext_vector_type(8)));
typedef float f32x2 __attribute__((ext_vector_type(2)));
typedef float f32x4 __attribute__((ext_vector_type(4)));
typedef float f32x16 __attribute__((ext_vector_type(16)));

#define DIM 256
#define NE 1024
#define NROWS 131072
#define DECAY 0.99f
#define ONE_MINUS 0.01f
#define EPS 1e-5f

// output offsets (floats) in d_out, concatenated in reference return order
#define OFF_Q    0u
#define OFF_DIFF 33554432u
#define OFF_IND  33554433u
#define OFF_NEMB 33685505u
#define OFF_NCS  33947649u
#define OFF_NEA  33948673u

#define MFMA32(a, b, c) __builtin_amdgcn_mfma_f32_32x32x16_f16(a, b, c, 0, 0, 0)

#define GLOAD16(gp, lp) __builtin_amdgcn_global_load_lds( \
    (__attribute__((address_space(1))) const void*)(gp),  \
    (__attribute__((address_space(3))) void*)(lp), 16, 0, 0)

// (distance, idx) -> u32 key; distances strictly positive -> IEEE bits
// monotonic. Low 10 mantissa bits carry idx (granularity ~0.016 << f16 noise).
static __device__ __forceinline__ unsigned packkey32(float v, int idx) {
    return (__float_as_uint(v) & 0xFFFFFC00u) | (unsigned)idx;
}
#define UMIN(a, b) ((b) < (a) ? (b) : (a))

// ---------------- K0_all: prep(64 blocks) + cvt(16384 blocks) + zeroing --------
__global__ void k0_all(const float* __restrict__ embed,
                       const float* __restrict__ input,
                       _Float16* __restrict__ bt_hi,
                       float* __restrict__ embT,
                       float* __restrict__ sqpart,
                       _Float16* __restrict__ qhiT,
                       int* __restrict__ counts,
                       int* __restrict__ cursors,
                       int* __restrict__ donecnt) {
    int t = threadIdx.x;
    if (blockIdx.x < 64) {
        __shared__ float T[64][65];
        int db = blockIdx.x & 3;
        int j0 = (blockIdx.x >> 2) * 64, d0 = db * 64;
        #pragma unroll
        for (int p = 0; p < 16; ++p) {
            int dd = p * 4 + (t >> 6), jj = t & 63;
            T[jj][dd] = embed[(size_t)(d0 + dd) * NE + j0 + jj];
        }
        __syncthreads();
        #pragma unroll
        for (int p = 0; p < 16; ++p) {
            int jj = p * 4 + (t >> 6), dd = t & 63;
            float e = T[jj][dd];
            int j = j0 + jj, d = d0 + dd;
            embT[(size_t)j * DIM + d] = e;
            bt_hi[(size_t)j * DIM + d] = (_Float16)e;
            float s = e * e;
            #pragma unroll
            for (int off = 32; off; off >>= 1) s += __shfl_down(s, off);
            if ((t & 63) == 0) sqpart[db * NE + j] = 0.5f * s;   // lane0 of wave
        }
    } else {
        int bc = blockIdx.x - 64;
        if (bc < 4) counts[bc * 256 + t] = 0;
        else if (bc < 8) cursors[(bc - 4) * 256 + t] = 0;
        if (bc == 8 && t == 0) *donecnt = 0;
        size_t D8 = (size_t)bc * 256 + t;   // half8 index
        int f = (int)(D8 >> 6);
        int lane = (int)(D8 & 63);
        int row = (f >> 4) * 32 + (lane & 31);
        int d = (f & 15) * 16 + (lane >> 5) * 8;
        const float* src = input + (size_t)row * DIM + d;
        f32x4 a = *(const f32x4*)src;
        f32x4 b = *(const f32x4*)(src + 4);
        half8 h;
        h[0] = (_Float16)a[0]; h[1] = (_Float16)a[1];
        h[2] = (_Float16)a[2]; h[3] = (_Float16)a[3];
        h[4] = (_Float16)b[0]; h[5] = (_Float16)b[1];
        h[6] = (_Float16)b[2]; h[7] = (_Float16)b[3];
        *(half8*)(qhiT + D8 * 8) = h;
    }
}

// ---------------- K1: code-resident GEMM, 8 waves share each LDS tile ---------
// 512 thr = 8 waves x 32 codes (A in AGPRs; 128-unified bucket, 4 waves/EU).
// Counted vmcnt(2), 2-deep dbuf. Block-level kred reduce (LDS) -> 4-wide part
// (R23's 32-wide part made k1b read 16MB strided = 85us latency-bound).
__global__ __launch_bounds__(512, 4)
void k1_stream(const _Float16* __restrict__ qhiT,
               const _Float16* __restrict__ bt_hi,
               const float* __restrict__ sqp,
               unsigned* __restrict__ part) {
    __shared__ _Float16 Xb[2][8192];            // 2 x 16KB m-tile
    __shared__ unsigned kred[2048];             // 8 waves x 256 rows
    const int b = blockIdx.x;
    const int q = (b >> 3) & 3;                 // code-block 0..3 (256 codes)
    const int r = (b & 7) + ((b >> 5) << 3);    // rowchunk 0..511 (XCD-colocated)
    const int tid = threadIdx.x;
    const int w = tid >> 6, l = tid & 63;
    const int l31 = l & 31, h = l >> 5;
    const int cq = q * 256 + w * 32;            // wave's 32 codes
    const int rowb = r * 256;
    const size_t tbase = (size_t)(r * 8) * 8192;  // halves; tile t at + t*8192

#define STAGE(t, bf) do {                                                  \
    const _Float16* sp_ = qhiT + tbase + (size_t)(t) * 8192 + tid * 8;     \
    _Float16* dp_ = &Xb[bf][tid * 8];                                      \
    GLOAD16(sp_ + 0,    dp_ + 0);                                          \
    GLOAD16(sp_ + 4096, dp_ + 4096);                                       \
} while (0)

    STAGE(0, 0);
    STAGE(1, 1);

    // A: lane holds code cq+l31, k-slice kb*16 + h*8 + 0..7 (loaded once)
    half8 A[16];
    {
        const _Float16* ap = bt_hi + (size_t)(cq + l31) * DIM + h * 8;
        #pragma unroll
        for (int kb = 0; kb < 16; ++kb) A[kb] = *(const half8*)(ap + kb * 16);
    }
    // sq for the lane's 16 D-rows: code = cq + (rr&3) + 8*(rr>>2) + 4*h
    float sq[16];
    #pragma unroll
    for (int rr = 0; rr < 16; ++rr) {
        int c = cq + (rr & 3) + 8 * (rr >> 2) + 4 * h;
        sq[rr] = (sqp[c] + sqp[NE + c]) + (sqp[2 * NE + c] + sqp[3 * NE + c]);
    }
    const int ibase = cq + 4 * h;

    __syncthreads();   // one-time full drain: tiles 0,1 + A + sq

    int buf = 0;
    #pragma unroll
    for (int m = 0; m < 8; ++m) {
        // own 2 tile-m loads landed; tile m+1's 2 stay in flight
        if (m == 7) { asm volatile("s_waitcnt vmcnt(0)" ::: "memory"); }
        else        { asm volatile("s_waitcnt vmcnt(2)" ::: "memory"); }
        __builtin_amdgcn_s_barrier();

        const _Float16* X = &Xb[buf][l * 8];
        f32x16 acc;
        #pragma unroll
        for (int e = 0; e < 16; ++e) acc[e] = 0.f;
        __builtin_amdgcn_s_setprio(1);
        #pragma unroll
        for (int kb = 0; kb < 16; ++kb) {
            half8 x = *(const half8*)(X + kb * 512);
            acc = MFMA32(A[kb], x, acc);
        }
        __builtin_amdgcn_s_setprio(0);
        __builtin_amdgcn_s_barrier();   // all waves done reading Xb[buf]

        // stage tile m+2 into the buffer just consumed
        if (m < 6) STAGE(m + 2, buf);

        // u32-key tree-min over the lane's 16 codes (register-only)
        unsigned k0 = packkey32(sq[0] - acc[0], ibase + 0);
        unsigned k1 = packkey32(sq[1] - acc[1], ibase + 1);
        unsigned k2 = packkey32(sq[2] - acc[2], ibase + 2);
        unsigned k3 = packkey32(sq[3] - acc[3], ibase + 3);
        unsigned k4 = packkey32(sq[4] - acc[4], ibase + 8);
        unsigned k5 = packkey32(sq[5] - acc[5], ibase + 9);
        unsigned k6 = packkey32(sq[6] - acc[6], ibase + 10);
        unsigned k7 = packkey32(sq[7] - acc[7], ibase + 11);
        unsigned k8 = packkey32(sq[8] - acc[8], ibase + 16);
        unsigned k9 = packkey32(sq[9] - acc[9], ibase + 17);
        unsigned ka = packkey32(sq[10] - acc[10], ibase + 18);
        unsigned kb_ = packkey32(sq[11] - acc[11], ibase + 19);
        unsigned kc = packkey32(sq[12] - acc[12], ibase + 24);
        unsigned kd = packkey32(sq[13] - acc[13], ibase + 25);
        unsigned ke = packkey32(sq[14] - acc[14], ibase + 26);
        unsigned kf = packkey32(sq[15] - acc[15], ibase + 27);
        k0 = UMIN(k0, k1); k2 = UMIN(k2, k3);
        k4 = UMIN(k4, k5); k6 = UMIN(k6, k7);
        k8 = UMIN(k8, k9); ka = UMIN(ka, kb_);
        kc = UMIN(kc, kd); ke = UMIN(ke, kf);
        k0 = UMIN(k0, k2); k4 = UMIN(k4, k6);
        k8 = UMIN(k8, ka); kc = UMIN(kc, ke);
        k0 = UMIN(k0, k4); k8 = UMIN(k8, kc);
        unsigned best = UMIN(k0, k8);
        // merge the lane pair sharing this row; park in LDS
        unsigned ok = __shfl_xor(best, 32);
        best = UMIN(best, ok);
        if (l < 32) kred[w * 256 + m * 32 + l31] = best;

        buf ^= 1;
    }

    __syncthreads();
    // block-level reduce: 8 wave-partials -> 1 per row; plain coalesced store
    if (tid < 256) {
        unsigned best = kred[tid];
        #pragma unroll
        for (int w2 = 1; w2 < 8; ++w2) best = UMIN(best, kred[w2 * 256 + tid]);
        part[(size_t)q * NROWS + rowb + tid] = best;
    }
}

// ---------------- K1b: 4 partials/row -> index/hist + zero esum; last block
// runs the scan/EMA-scalar body (fused former k2).
__global__ __launch_bounds__(1024)
void k1b_idx(const unsigned* __restrict__ part,
             const float* __restrict__ cluster_size,
             float* __restrict__ out,
             int* __restrict__ jint,
             int* __restrict__ counts,
             float* __restrict__ embed_sum,
             int* __restrict__ offsets,
             float* __restrict__ cs_ws,
             int* __restrict__ donecnt) {
    __shared__ int   wtot[16];
    __shared__ float wsum[16];
    __shared__ int lastflag;
    int t = threadIdx.x;
    int row = blockIdx.x * 1024 + t;
    // zero embed_sum inline (bt_hi overlay dead after k1_stream)
    ((f32x2*)embed_sum)[row] = (f32x2){0.f, 0.f};
    unsigned best = part[row];
    #pragma unroll
    for (int qw = 1; qw < 4; ++qw) {
        unsigned v = part[(size_t)qw * NROWS + row];
        best = UMIN(best, v);
    }
    int jm = (int)(best & 0x3FFu);
    out[OFF_IND + row] = (float)jm;
    jint[row] = jm;
    atomicAdd(&counts[jm], 1);

    // last-block election (saves one kernel-launch boundary)
    __threadfence();
    __syncthreads();
    if (t == 0) lastflag = (atomicAdd(donecnt, 1) == 127) ? 1 : 0;
    __syncthreads();
    if (!lastflag) return;

    // ---- scan/EMA-scalar body (identical math to the former k2_small) ----
    int w = t >> 6, l = t & 63;
    int cnt = atomicAdd(&counts[t], 0);   // device-scope read
    float ncs = cluster_size[t] * DECAY + ONE_MINUS * (float)cnt;
    out[OFF_NCS + t] = ncs;

    int sc = cnt;
    #pragma unroll
    for (int off = 1; off < 64; off <<= 1) {
        int v = __shfl_up(sc, off);
        if (l >= off) sc += v;
    }
    float ws = ncs;
    #pragma unroll
    for (int off = 32; off; off >>= 1) ws += __shfl_xor(ws, off);
    if (l == 63) wtot[w] = sc;
    if (l == 0) wsum[w] = ws;
    __syncthreads();
    int woff = 0; float n = 0.f;
    #pragma unroll
    for (int i = 0; i < 16; ++i) {
        woff += (i < w) ? wtot[i] : 0;
        n += wsum[i];
    }
    offsets[t] = woff + sc - cnt;       // exclusive prefix
    cs_ws[t] = (ncs + EPS) / (n + (float)NE * EPS) * n;
}

// ---------------- K3: scatter row ids into per-code buckets ----------------
__global__ void k3_scatter(const int* __restrict__ jint,
                           const int* __restrict__ offsets,
                           int* __restrict__ cursors,
                           int* __restrict__ list) {
    int r = blockIdx.x * 256 + threadIdx.x;
    int j = jint[r];
    int pos = atomicAdd(&cursors[j], 1);
    list[offsets[j] + pos] = r;
}

// ---------------- K4: FUSED balanced segment sum + quantize write + diff ------
#define K4FLUSH() do {                                                   \
    float* dst = embed_sum + (size_t)curj * DIM + l * 4;                 \
    atomicAdd(dst + 0, acc[0]); atomicAdd(dst + 1, acc[1]);              \
    atomicAdd(dst + 2, acc[2]); atomicAdd(dst + 3, acc[3]);              \
    acc[0] = acc[1] = acc[2] = acc[3] = 0.f;                             \
} while (0)

__global__ void k4_segsum(const float* __restrict__ input,
                          const int* __restrict__ jint,
                          const int* __restrict__ list,
                          const float* __restrict__ embT,
                          float* __restrict__ out,
                          float* __restrict__ embed_sum,
                          float* __restrict__ diffpart) {
    __shared__ float dred[4];
    int wid = (blockIdx.x * 256 + threadIdx.x) >> 6;   // 0..4095
    int w = (threadIdx.x >> 6), l = threadIdx.x & 63;
    int p0 = wid * 32;
    int row_l = list[p0 + (l & 31)];
    int j_l = jint[row_l];
    f32x4 acc = {0.f, 0.f, 0.f, 0.f};
    float dsum = 0.f;
    int curj = __shfl(j_l, 0);
    #pragma unroll 1
    for (int g = 0; g < 8; ++g) {
        int r0 = __shfl(row_l, 4 * g + 0), j0 = __shfl(j_l, 4 * g + 0);
        int r1 = __shfl(row_l, 4 * g + 1), j1 = __shfl(j_l, 4 * g + 1);
        int r2 = __shfl(row_l, 4 * g + 2), j2 = __shfl(j_l, 4 * g + 2);
        int r3 = __shfl(row_l, 4 * g + 3), j3 = __shfl(j_l, 4 * g + 3);
        f32x4 v0 = *(const f32x4*)(input + (size_t)r0 * DIM + l * 4);
        f32x4 v1 = *(const f32x4*)(input + (size_t)r1 * DIM + l * 4);
        f32x4 v2 = *(const f32x4*)(input + (size_t)r2 * DIM + l * 4);
        f32x4 v3 = *(const f32x4*)(input + (size_t)r3 * DIM + l * 4);
        f32x4 q0 = *(const f32x4*)(embT + (size_t)j0 * DIM + l * 4);
        f32x4 q1 = *(const f32x4*)(embT + (size_t)j1 * DIM + l * 4);
        f32x4 q2 = *(const f32x4*)(embT + (size_t)j2 * DIM + l * 4);
        f32x4 q3 = *(const f32x4*)(embT + (size_t)j3 * DIM + l * 4);
        *(f32x4*)(out + OFF_Q + (size_t)r0 * DIM + l * 4) = q0;
        *(f32x4*)(out + OFF_Q + (size_t)r1 * DIM + l * 4) = q1;
        *(f32x4*)(out + OFF_Q + (size_t)r2 * DIM + l * 4) = q2;
        *(f32x4*)(out + OFF_Q + (size_t)r3 * DIM + l * 4) = q3;
        f32x4 e0 = q0 - v0, e1 = q1 - v1, e2 = q2 - v2, e3 = q3 - v3;
        dsum += e0[0]*e0[0] + e0[1]*e0[1] + e0[2]*e0[2] + e0[3]*e0[3];
        dsum += e1[0]*e1[0] + e1[1]*e1[1] + e1[2]*e1[2] + e1[3]*e1[3];
        dsum += e2[0]*e2[0] + e2[1]*e2[1] + e2[2]*e2[2] + e2[3]*e2[3];
        dsum += e3[0]*e3[0] + e3[1]*e3[1] + e3[2]*e3[2] + e3[3]*e3[3];
        if (j0 != curj) { K4FLUSH(); curj = j0; }
        acc += v0;
        if (j1 != curj) { K4FLUSH(); curj = j1; }
        acc += v1;
        if (j2 != curj) { K4FLUSH(); curj = j2; }
        acc += v2;
        if (j3 != curj) { K4FLUSH(); curj = j3; }
        acc += v3;
    }
    K4FLUSH();
    for (int off = 32; off; off >>= 1) dsum += __shfl_down(dsum, off);
    if (l == 0) dred[w] = dsum;
    __syncthreads();
    if (threadIdx.x == 0)
        diffpart[blockIdx.x] = dred[0] + dred[1] + dred[2] + dred[3];
}

// ---------------- K5: transpose + EMA outputs + diff finalize (merged) --------
__global__ void k5_ema(const float* __restrict__ embed_sum,
                       const float* __restrict__ embed_avg,
                       const float* __restrict__ cs_ws,
                       const float* __restrict__ diffpart,
                       float* __restrict__ out) {
    __shared__ float T[64][65];
    __shared__ float dsh[4];
    int t = threadIdx.x;
    bool b0 = (blockIdx.x == 0) && (blockIdx.y == 0);
    if (b0) {
        float dp = (diffpart[t] + diffpart[t + 256])
                 + (diffpart[t + 512] + diffpart[t + 768]);
        #pragma unroll
        for (int off = 32; off; off >>= 1) dp += __shfl_xor(dp, off);
        if ((t & 63) == 0) dsh[t >> 6] = dp;
    }
    int j0 = blockIdx.x * 64, d0 = blockIdx.y * 64;
    #pragma unroll
    for (int p = 0; p < 16; ++p) {
        int jj = p * 4 + (t >> 6), dd = t & 63;
        T[dd][jj] = embed_sum[(size_t)(j0 + jj) * DIM + d0 + dd];
    }
    __syncthreads();
    if (b0 && t == 0)
        out[OFF_DIFF] = ((dsh[0] + dsh[1]) + (dsh[2] + dsh[3])) / 33554432.0f;
    #pragma unroll
    for (int p = 0; p < 16; ++p) {
        int dd = p * 4 + (t >> 6), jj = t & 63;
        int d = d0 + dd, j = j0 + jj;
        float sum = T[dd][jj];
        float na = embed_avg[(size_t)d * NE + j] * DECAY + ONE_MINUS * sum;
        out[OFF_NEA + (size_t)d * NE + j] = na;
        out[OFF_NEMB + (size_t)d * NE + j] = na / cs_ws[j];
    }
}

extern "C" void kernel_launch(void* const* d_in, const int* in_sizes, int n_in,
                              void* d_out, int out_size, void* d_ws, size_t ws_size,
                              hipStream_t stream) {
    const float* input        = (const float*)d_in[0];
    const float* embed        = (const float*)d_in[1];
    const float* cluster_size = (const float*)d_in[2];
    const float* embed_avg    = (const float*)d_in[3];
    float* out = (float*)d_out;
    char* ws = (char*)d_ws;

    _Float16* bt_hi  = (_Float16*)(ws + 0);             // 512 KB
    float*    embT   = (float*)(ws + 1048576);          // 1 MB
    int*      counts = (int*)(ws + 2101248);
    int*      offsets= (int*)(ws + 2105344);
    int*      cursors= (int*)(ws + 2113536);
    int*      jint   = (int*)(ws + 2117632);            // 512 KB
    int*      list   = (int*)(ws + 2641920);            // 512 KB
    float*    diffpart = (float*)(ws + 3166208);        // 1024 floats
    float*    cs_ws  = (float*)(ws + 3174400);          // 4 KB
    float*    sqpart = (float*)(ws + 3178496);          // 16 KB
    int*      donecnt = (int*)(ws + 3194880);           // 4 B
    // embed_sum overlays the dead bt_hi region after k1_stream
    float*    embed_sum = (float*)(ws + 0);             // [1024][256] f32
    // scratch inside the out-Q region (dead before k4 writes Q):
    //   qhiT: fragment-major f16 input plane, 64 MiB at Q[0..)
    //   part: 4 u32 partial keys per row, 2 MiB at Q+64MiB
    _Float16* qhiT = (_Float16*)(out + OFF_Q);
    unsigned* part = (unsigned*)((char*)(out + OFF_Q) + (64u << 20));

    k0_all<<<16448, 256, 0, stream>>>(embed, input, bt_hi, embT, sqpart,
                                      qhiT, counts, cursors, donecnt);
    k1_stream<<<2048, 512, 0, stream>>>(qhiT, bt_hi, sqpart, part);
    k1b_idx<<<128, 1024, 0, stream>>>(part, cluster_size, out, jint, counts,
                                      embed_sum, offsets, cs_ws, donecnt);
    k3_scatter<<<512, 256, 0, stream>>>(jint, offsets, cursors, list);
    k4_segsum<<<1024, 256, 0, stream>>>(input, jint, list, embT, out, embed_sum, diffpart);
    k5_ema<<<dim3(16, 4), 256, 0, stream>>>(embed_sum, embed_avg, cs_ws, diffpart, out);
}

// Round 25
// 246.213 us; speedup vs baseline: 1.2828x; 1.2814x over previous
//
#include <hip/hip_runtime.h>

typedef _Float16 half8 __attribute__((ext_vector_type(8)));
typedef float f32x2 __attribute__((ext_vector_type(2)));
typedef float f32x4 __attribute__((ext_vector_type(4)));
typedef float f32x16 __attribute__((ext_vector_type(16)));

#define DIM 256
#define NE 1024
#define NROWS 131072
#define DECAY 0.99f
#define ONE_MINUS 0.01f
#define EPS 1e-5f

// output offsets (floats) in d_out, concatenated in reference return order
#define OFF_Q    0u
#define OFF_DIFF 33554432u
#define OFF_IND  33554433u
#define OFF_NEMB 33685505u
#define OFF_NCS  33947649u
#define OFF_NEA  33948673u

#define MFMA32(a, b, c) __builtin_amdgcn_mfma_f32_32x32x16_f16(a, b, c, 0, 0, 0)

#define GLOAD16(gp, lp) __builtin_amdgcn_global_load_lds( \
    (__attribute__((address_space(1))) const void*)(gp),  \
    (__attribute__((address_space(3))) void*)(lp), 16, 0, 0)

// (distance, idx) -> u32 key; distances strictly positive -> IEEE bits
// monotonic. Low 10 mantissa bits carry idx (granularity ~0.016 << f16 noise).
static __device__ __forceinline__ unsigned packkey32(float v, int idx) {
    return (__float_as_uint(v) & 0xFFFFFC00u) | (unsigned)idx;
}
#define UMIN(a, b) ((b) < (a) ? (b) : (a))

// ---------------- K0_all: prep(64 blocks) + cvt(16384 blocks) + zeroing --------
__global__ void k0_all(const float* __restrict__ embed,
                       const float* __restrict__ input,
                       _Float16* __restrict__ bt_hi,
                       float* __restrict__ embT,
                       float* __restrict__ sqpart,
                       _Float16* __restrict__ qhiT,
                       int* __restrict__ counts,
                       int* __restrict__ cursors,
                       int* __restrict__ donecnt) {
    int t = threadIdx.x;
    if (blockIdx.x < 64) {
        __shared__ float T[64][65];
        int db = blockIdx.x & 3;
        int j0 = (blockIdx.x >> 2) * 64, d0 = db * 64;
        #pragma unroll
        for (int p = 0; p < 16; ++p) {
            int dd = p * 4 + (t >> 6), jj = t & 63;
            T[jj][dd] = embed[(size_t)(d0 + dd) * NE + j0 + jj];
        }
        __syncthreads();
        #pragma unroll
        for (int p = 0; p < 16; ++p) {
            int jj = p * 4 + (t >> 6), dd = t & 63;
            float e = T[jj][dd];
            int j = j0 + jj, d = d0 + dd;
            embT[(size_t)j * DIM + d] = e;
            bt_hi[(size_t)j * DIM + d] = (_Float16)e;
            float s = e * e;
            #pragma unroll
            for (int off = 32; off; off >>= 1) s += __shfl_down(s, off);
            if ((t & 63) == 0) sqpart[db * NE + j] = 0.5f * s;   // lane0 of wave
        }
    } else {
        int bc = blockIdx.x - 64;
        if (bc < 4) counts[bc * 256 + t] = 0;
        else if (bc < 8) cursors[(bc - 4) * 256 + t] = 0;
        if (bc == 8 && t == 0) *donecnt = 0;
        size_t D8 = (size_t)bc * 256 + t;   // half8 index
        int f = (int)(D8 >> 6);
        int lane = (int)(D8 & 63);
        int row = (f >> 4) * 32 + (lane & 31);
        int d = (f & 15) * 16 + (lane >> 5) * 8;
        const float* src = input + (size_t)row * DIM + d;
        f32x4 a = *(const f32x4*)src;
        f32x4 b = *(const f32x4*)(src + 4);
        half8 h;
        h[0] = (_Float16)a[0]; h[1] = (_Float16)a[1];
        h[2] = (_Float16)a[2]; h[3] = (_Float16)a[3];
        h[4] = (_Float16)b[0]; h[5] = (_Float16)b[1];
        h[6] = (_Float16)b[2]; h[7] = (_Float16)b[3];
        *(half8*)(qhiT + D8 * 8) = h;
    }
}

// ---------------- K1: code-resident GEMM, 8 waves share each LDS tile ---------
// 512 thr = 8 waves x 32 codes (A in AGPRs; 128-unified bucket, 4 waves/EU).
// Counted vmcnt(2), 2-deep dbuf. Block-level kred reduce -> 4-wide part.
__global__ __launch_bounds__(512, 4)
void k1_stream(const _Float16* __restrict__ qhiT,
               const _Float16* __restrict__ bt_hi,
               const float* __restrict__ sqp,
               unsigned* __restrict__ part) {
    __shared__ _Float16 Xb[2][8192];            // 2 x 16KB m-tile
    __shared__ unsigned kred[2048];             // 8 waves x 256 rows
    const int b = blockIdx.x;
    const int q = (b >> 3) & 3;                 // code-block 0..3 (256 codes)
    const int r = (b & 7) + ((b >> 5) << 3);    // rowchunk 0..511 (XCD-colocated)
    const int tid = threadIdx.x;
    const int w = tid >> 6, l = tid & 63;
    const int l31 = l & 31, h = l >> 5;
    const int cq = q * 256 + w * 32;            // wave's 32 codes
    const int rowb = r * 256;
    const size_t tbase = (size_t)(r * 8) * 8192;  // halves; tile t at + t*8192

#define STAGE(t, bf) do {                                                  \
    const _Float16* sp_ = qhiT + tbase + (size_t)(t) * 8192 + tid * 8;     \
    _Float16* dp_ = &Xb[bf][tid * 8];                                      \
    GLOAD16(sp_ + 0,    dp_ + 0);                                          \
    GLOAD16(sp_ + 4096, dp_ + 4096);                                       \
} while (0)

    STAGE(0, 0);
    STAGE(1, 1);

    // A: lane holds code cq+l31, k-slice kb*16 + h*8 + 0..7 (loaded once)
    half8 A[16];
    {
        const _Float16* ap = bt_hi + (size_t)(cq + l31) * DIM + h * 8;
        #pragma unroll
        for (int kb = 0; kb < 16; ++kb) A[kb] = *(const half8*)(ap + kb * 16);
    }
    // sq for the lane's 16 D-rows: code = cq + (rr&3) + 8*(rr>>2) + 4*h
    float sq[16];
    #pragma unroll
    for (int rr = 0; rr < 16; ++rr) {
        int c = cq + (rr & 3) + 8 * (rr >> 2) + 4 * h;
        sq[rr] = (sqp[c] + sqp[NE + c]) + (sqp[2 * NE + c] + sqp[3 * NE + c]);
    }
    const int ibase = cq + 4 * h;

    __syncthreads();   // one-time full drain: tiles 0,1 + A + sq

    int buf = 0;
    #pragma unroll
    for (int m = 0; m < 8; ++m) {
        // own 2 tile-m loads landed; tile m+1's 2 stay in flight
        if (m == 7) { asm volatile("s_waitcnt vmcnt(0)" ::: "memory"); }
        else        { asm volatile("s_waitcnt vmcnt(2)" ::: "memory"); }
        __builtin_amdgcn_s_barrier();

        const _Float16* X = &Xb[buf][l * 8];
        f32x16 acc;
        #pragma unroll
        for (int e = 0; e < 16; ++e) acc[e] = 0.f;
        __builtin_amdgcn_s_setprio(1);
        #pragma unroll
        for (int kb = 0; kb < 16; ++kb) {
            half8 x = *(const half8*)(X + kb * 512);
            acc = MFMA32(A[kb], x, acc);
        }
        __builtin_amdgcn_s_setprio(0);
        __builtin_amdgcn_s_barrier();   // all waves done reading Xb[buf]

        // stage tile m+2 into the buffer just consumed
        if (m < 6) STAGE(m + 2, buf);

        // u32-key tree-min over the lane's 16 codes (register-only)
        unsigned k0 = packkey32(sq[0] - acc[0], ibase + 0);
        unsigned k1 = packkey32(sq[1] - acc[1], ibase + 1);
        unsigned k2 = packkey32(sq[2] - acc[2], ibase + 2);
        unsigned k3 = packkey32(sq[3] - acc[3], ibase + 3);
        unsigned k4 = packkey32(sq[4] - acc[4], ibase + 8);
        unsigned k5 = packkey32(sq[5] - acc[5], ibase + 9);
        unsigned k6 = packkey32(sq[6] - acc[6], ibase + 10);
        unsigned k7 = packkey32(sq[7] - acc[7], ibase + 11);
        unsigned k8 = packkey32(sq[8] - acc[8], ibase + 16);
        unsigned k9 = packkey32(sq[9] - acc[9], ibase + 17);
        unsigned ka = packkey32(sq[10] - acc[10], ibase + 18);
        unsigned kb_ = packkey32(sq[11] - acc[11], ibase + 19);
        unsigned kc = packkey32(sq[12] - acc[12], ibase + 24);
        unsigned kd = packkey32(sq[13] - acc[13], ibase + 25);
        unsigned ke = packkey32(sq[14] - acc[14], ibase + 26);
        unsigned kf = packkey32(sq[15] - acc[15], ibase + 27);
        k0 = UMIN(k0, k1); k2 = UMIN(k2, k3);
        k4 = UMIN(k4, k5); k6 = UMIN(k6, k7);
        k8 = UMIN(k8, k9); ka = UMIN(ka, kb_);
        kc = UMIN(kc, kd); ke = UMIN(ke, kf);
        k0 = UMIN(k0, k2); k4 = UMIN(k4, k6);
        k8 = UMIN(k8, ka); kc = UMIN(kc, ke);
        k0 = UMIN(k0, k4); k8 = UMIN(k8, kc);
        unsigned best = UMIN(k0, k8);
        // merge the lane pair sharing this row; park in LDS
        unsigned ok = __shfl_xor(best, 32);
        best = UMIN(best, ok);
        if (l < 32) kred[w * 256 + m * 32 + l31] = best;

        buf ^= 1;
    }

    __syncthreads();
    // block-level reduce: 8 wave-partials -> 1 per row; plain coalesced store
    if (tid < 256) {
        unsigned best = kred[tid];
        #pragma unroll
        for (int w2 = 1; w2 < 8; ++w2) best = UMIN(best, kred[w2 * 256 + tid]);
        part[(size_t)q * NROWS + rowb + tid] = best;
    }
}

// ---------------- K1b: 4 partials/row -> index + LDS histogram; last block
// runs the scan/EMA-scalar body (fused former k2).
// R24 lesson: per-thread __threadfence (L2-writeback per wave on multi-XCD)
// + 131K contended global atomics = 87us at 0% VALU. Fix: LDS histogram
// (even 128-deep global contention) and NO threadfence -- __syncthreads
// drains vmcnt(0), so all count-atomics are at the coherent point before
// thread 0's donecnt election atomic; reader uses atomic loads.
__global__ __launch_bounds__(1024)
void k1b_idx(const unsigned* __restrict__ part,
             const float* __restrict__ cluster_size,
             float* __restrict__ out,
             int* __restrict__ jint,
             int* __restrict__ counts,
             float* __restrict__ embed_sum,
             int* __restrict__ offsets,
             float* __restrict__ cs_ws,
             int* __restrict__ donecnt) {
    __shared__ int hist[NE];
    __shared__ int   wtot[16];
    __shared__ float wsum[16];
    __shared__ int lastflag;
    int t = threadIdx.x;
    hist[t] = 0;
    int row = blockIdx.x * 1024 + t;
    // zero embed_sum inline (bt_hi overlay dead after k1_stream)
    ((f32x2*)embed_sum)[row] = (f32x2){0.f, 0.f};
    unsigned best = part[row];
    #pragma unroll
    for (int qw = 1; qw < 4; ++qw) {
        unsigned v = part[(size_t)qw * NROWS + row];
        best = UMIN(best, v);
    }
    int jm = (int)(best & 0x3FFu);
    out[OFF_IND + row] = (float)jm;
    jint[row] = jm;
    __syncthreads();                 // hist zeroed
    atomicAdd(&hist[jm], 1);         // LDS atomic (cheap even when contended)
    __syncthreads();
    int hc = hist[t];
    if (hc) atomicAdd(&counts[t], hc);   // <=1024 adds/block, evenly spread

    // last-block election (atomics complete before the barrier's vmcnt drain)
    __syncthreads();
    if (t == 0) lastflag = (atomicAdd(donecnt, 1) == 127) ? 1 : 0;
    __syncthreads();
    if (!lastflag) return;

    // ---- scan/EMA-scalar body (identical math to the former k2_small) ----
    int w = t >> 6, l = t & 63;
    int cnt = atomicAdd(&counts[t], 0);   // atomic read at coherent point
    float ncs = cluster_size[t] * DECAY + ONE_MINUS * (float)cnt;
    out[OFF_NCS + t] = ncs;

    int sc = cnt;
    #pragma unroll
    for (int off = 1; off < 64; off <<= 1) {
        int v = __shfl_up(sc, off);
        if (l >= off) sc += v;
    }
    float ws = ncs;
    #pragma unroll
    for (int off = 32; off; off >>= 1) ws += __shfl_xor(ws, off);
    if (l == 63) wtot[w] = sc;
    if (l == 0) wsum[w] = ws;
    __syncthreads();
    int woff = 0; float n = 0.f;
    #pragma unroll
    for (int i = 0; i < 16; ++i) {
        woff += (i < w) ? wtot[i] : 0;
        n += wsum[i];
    }
    offsets[t] = woff + sc - cnt;       // exclusive prefix
    cs_ws[t] = (ncs + EPS) / (n + (float)NE * EPS) * n;
}

// ---------------- K3: scatter row ids into per-code buckets ----------------
__global__ void k3_scatter(const int* __restrict__ jint,
                           const int* __restrict__ offsets,
                           int* __restrict__ cursors,
                           int* __restrict__ list) {
    int r = blockIdx.x * 256 + threadIdx.x;
    int j = jint[r];
    int pos = atomicAdd(&cursors[j], 1);
    list[offsets[j] + pos] = r;
}

// ---------------- K4: FUSED balanced segment sum + quantize write + diff ------
#define K4FLUSH() do {                                                   \
    float* dst = embed_sum + (size_t)curj * DIM + l * 4;                 \
    atomicAdd(dst + 0, acc[0]); atomicAdd(dst + 1, acc[1]);              \
    atomicAdd(dst + 2, acc[2]); atomicAdd(dst + 3, acc[3]);              \
    acc[0] = acc[1] = acc[2] = acc[3] = 0.f;                             \
} while (0)

__global__ void k4_segsum(const float* __restrict__ input,
                          const int* __restrict__ jint,
                          const int* __restrict__ list,
                          const float* __restrict__ embT,
                          float* __restrict__ out,
                          float* __restrict__ embed_sum,
                          float* __restrict__ diffpart) {
    __shared__ float dred[4];
    int wid = (blockIdx.x * 256 + threadIdx.x) >> 6;   // 0..4095
    int w = (threadIdx.x >> 6), l = threadIdx.x & 63;
    int p0 = wid * 32;
    int row_l = list[p0 + (l & 31)];
    int j_l = jint[row_l];
    f32x4 acc = {0.f, 0.f, 0.f, 0.f};
    float dsum = 0.f;
    int curj = __shfl(j_l, 0);
    #pragma unroll 1
    for (int g = 0; g < 8; ++g) {
        int r0 = __shfl(row_l, 4 * g + 0), j0 = __shfl(j_l, 4 * g + 0);
        int r1 = __shfl(row_l, 4 * g + 1), j1 = __shfl(j_l, 4 * g + 1);
        int r2 = __shfl(row_l, 4 * g + 2), j2 = __shfl(j_l, 4 * g + 2);
        int r3 = __shfl(row_l, 4 * g + 3), j3 = __shfl(j_l, 4 * g + 3);
        f32x4 v0 = *(const f32x4*)(input + (size_t)r0 * DIM + l * 4);
        f32x4 v1 = *(const f32x4*)(input + (size_t)r1 * DIM + l * 4);
        f32x4 v2 = *(const f32x4*)(input + (size_t)r2 * DIM + l * 4);
        f32x4 v3 = *(const f32x4*)(input + (size_t)r3 * DIM + l * 4);
        f32x4 q0 = *(const f32x4*)(embT + (size_t)j0 * DIM + l * 4);
        f32x4 q1 = *(const f32x4*)(embT + (size_t)j1 * DIM + l * 4);
        f32x4 q2 = *(const f32x4*)(embT + (size_t)j2 * DIM + l * 4);
        f32x4 q3 = *(const f32x4*)(embT + (size_t)j3 * DIM + l * 4);
        *(f32x4*)(out + OFF_Q + (size_t)r0 * DIM + l * 4) = q0;
        *(f32x4*)(out + OFF_Q + (size_t)r1 * DIM + l * 4) = q1;
        *(f32x4*)(out + OFF_Q + (size_t)r2 * DIM + l * 4) = q2;
        *(f32x4*)(out + OFF_Q + (size_t)r3 * DIM + l * 4) = q3;
        f32x4 e0 = q0 - v0, e1 = q1 - v1, e2 = q2 - v2, e3 = q3 - v3;
        dsum += e0[0]*e0[0] + e0[1]*e0[1] + e0[2]*e0[2] + e0[3]*e0[3];
        dsum += e1[0]*e1[0] + e1[1]*e1[1] + e1[2]*e1[2] + e1[3]*e1[3];
        dsum += e2[0]*e2[0] + e2[1]*e2[1] + e2[2]*e2[2] + e2[3]*e2[3];
        dsum += e3[0]*e3[0] + e3[1]*e3[1] + e3[2]*e3[2] + e3[3]*e3[3];
        if (j0 != curj) { K4FLUSH(); curj = j0; }
        acc += v0;
        if (j1 != curj) { K4FLUSH(); curj = j1; }
        acc += v1;
        if (j2 != curj) { K4FLUSH(); curj = j2; }
        acc += v2;
        if (j3 != curj) { K4FLUSH(); curj = j3; }
        acc += v3;
    }
    K4FLUSH();
    for (int off = 32; off; off >>= 1) dsum += __shfl_down(dsum, off);
    if (l == 0) dred[w] = dsum;
    __syncthreads();
    if (threadIdx.x == 0)
        diffpart[blockIdx.x] = dred[0] + dred[1] + dred[2] + dred[3];
}

// ---------------- K5: transpose + EMA outputs + diff finalize (merged) --------
__global__ void k5_ema(const float* __restrict__ embed_sum,
                       const float* __restrict__ embed_avg,
                       const float* __restrict__ cs_ws,
                       const float* __restrict__ diffpart,
                       float* __restrict__ out) {
    __shared__ float T[64][65];
    __shared__ float dsh[4];
    int t = threadIdx.x;
    bool b0 = (blockIdx.x == 0) && (blockIdx.y == 0);
    if (b0) {
        float dp = (diffpart[t] + diffpart[t + 256])
                 + (diffpart[t + 512] + diffpart[t + 768]);
        #pragma unroll
        for (int off = 32; off; off >>= 1) dp += __shfl_xor(dp, off);
        if ((t & 63) == 0) dsh[t >> 6] = dp;
    }
    int j0 = blockIdx.x * 64, d0 = blockIdx.y * 64;
    #pragma unroll
    for (int p = 0; p < 16; ++p) {
        int jj = p * 4 + (t >> 6), dd = t & 63;
        T[dd][jj] = embed_sum[(size_t)(j0 + jj) * DIM + d0 + dd];
    }
    __syncthreads();
    if (b0 && t == 0)
        out[OFF_DIFF] = ((dsh[0] + dsh[1]) + (dsh[2] + dsh[3])) / 33554432.0f;
    #pragma unroll
    for (int p = 0; p < 16; ++p) {
        int dd = p * 4 + (t >> 6), jj = t & 63;
        int d = d0 + dd, j = j0 + jj;
        float sum = T[dd][jj];
        float na = embed_avg[(size_t)d * NE + j] * DECAY + ONE_MINUS * sum;
        out[OFF_NEA + (size_t)d * NE + j] = na;
        out[OFF_NEMB + (size_t)d * NE + j] = na / cs_ws[j];
    }
}

extern "C" void kernel_launch(void* const* d_in, const int* in_sizes, int n_in,
                              void* d_out, int out_size, void* d_ws, size_t ws_size,
                              hipStream_t stream) {
    const float* input        = (const float*)d_in[0];
    const float* embed        = (const float*)d_in[1];
    const float* cluster_size = (const float*)d_in[2];
    const float* embed_avg    = (const float*)d_in[3];
    float* out = (float*)d_out;
    char* ws = (char*)d_ws;

    _Float16* bt_hi  = (_Float16*)(ws + 0);             // 512 KB
    float*    embT   = (float*)(ws + 1048576);          // 1 MB
    int*      counts = (int*)(ws + 2101248);
    int*      offsets= (int*)(ws + 2105344);
    int*      cursors= (int*)(ws + 2113536);
    int*      jint   = (int*)(ws + 2117632);            // 512 KB
    int*      list   = (int*)(ws + 2641920);            // 512 KB
    float*    diffpart = (float*)(ws + 3166208);        // 1024 floats
    float*    cs_ws  = (float*)(ws + 3174400);          // 4 KB
    float*    sqpart = (float*)(ws + 3178496);          // 16 KB
    int*      donecnt = (int*)(ws + 3194880);           // 4 B
    // embed_sum overlays the dead bt_hi region after k1_stream
    float*    embed_sum = (float*)(ws + 0);             // [1024][256] f32
    // scratch inside the out-Q region (dead before k4 writes Q):
    //   qhiT: fragment-major f16 input plane, 64 MiB at Q[0..)
    //   part: 4 u32 partial keys per row, 2 MiB at Q+64MiB
    _Float16* qhiT = (_Float16*)(out + OFF_Q);
    unsigned* part = (unsigned*)((char*)(out + OFF_Q) + (64u << 20));

    k0_all<<<16448, 256, 0, stream>>>(embed, input, bt_hi, embT, sqpart,
                                      qhiT, counts, cursors, donecnt);
    k1_stream<<<2048, 512, 0, stream>>>(qhiT, bt_hi, sqpart, part);
    k1b_idx<<<128, 1024, 0, stream>>>(part, cluster_size, out, jint, counts,
                                      embed_sum, offsets, cs_ws, donecnt);
    k3_scatter<<<512, 256, 0, stream>>>(jint, offsets, cursors, list);
    k4_segsum<<<1024, 256, 0, stream>>>(input, jint, list, embT, out, embed_sum, diffpart);
    k5_ema<<<dim3(16, 4), 256, 0, stream>>>(embed_sum, embed_avg, cs_ws, diffpart, out);
}